// Round 8
// baseline (1289.388 us; speedup 1.0000x reference)
//
#include <hip/hip_runtime.h>
#include <hip/hip_bf16.h>
#include <math.h>

#define NEG_SLOPE 0.2f

static const int NN = 100000;   // nodes per branch
static const int EE = 1600000;  // edges per branch
static const int BB = 512;      // graphs
static const int DD = 256;      // input dim
static const int NBUK = (NN + 511) / 512;   // 196 buckets of 512 nodes
static const int CAP4 = 2560;               // per-sub-bucket capacity (mean 2041, >11 sigma)

typedef __attribute__((ext_vector_type(8))) short bf16x8;
typedef __attribute__((ext_vector_type(4))) float f32x4;

__device__ __forceinline__ float leaky(float x) { return x >= 0.f ? x : NEG_SLOPE * x; }

__device__ __forceinline__ unsigned short f2b(float f) {
    __hip_bfloat16 h = __float2bfloat16(f);   // RNE
    return *reinterpret_cast<unsigned short*>(&h);
}
__device__ __forceinline__ float b2f_lo(unsigned v) { return __uint_as_float(v << 16); }
__device__ __forceinline__ float b2f_hi(unsigned v) { return __uint_as_float(v & 0xFFFF0000u); }
__device__ __forceinline__ unsigned packb(float a, float b) {
    return (unsigned)f2b(a) | ((unsigned)f2b(b) << 16);
}

// ---------------- W^T cast: WT[n][k] = bf16(W[k][n]) ----------------
__global__ void wt_kernel(const float* __restrict__ W, unsigned short* __restrict__ WT,
                          int K, int N) {
    int idx = blockIdx.x * blockDim.x + threadIdx.x;
    if (idx >= K * N) return;
    int n = idx / K, k = idx - n * K;
    WT[idx] = f2b(W[(size_t)k * N + n]);
}

// ---- fused MFMA GEMM: hb = packed-bf16(bf16(A)@bf16(W)); al_s/al_d = h·a_src / h·a_dst.
//      32 rows/wave, 128 rows/block. ABF: A is bf16 (ushort) instead of f32. ----
template <int K, int N, bool ABF>
__global__ __launch_bounds__(256, 2) void gemm_fused_kernel(const void* __restrict__ Av,
                                                            const unsigned short* __restrict__ WT,
                                                            const float* __restrict__ a_src,
                                                            const float* __restrict__ a_dst,
                                                            unsigned* __restrict__ hb,
                                                            float* __restrict__ al_s,
                                                            float* __restrict__ al_d, int M) {
    constexpr int NT = N / 16;
    const int l = threadIdx.x & 63;
    const int w = threadIdx.x >> 6;
    const int rl = l & 15;
    const int kh = l >> 4;
    const int wrow0 = blockIdx.x * 128 + w * 32;
    const int r0 = min(wrow0 + rl, M - 1);
    const int r1 = min(wrow0 + 16 + rl, M - 1);

    f32x4 acc[2][NT];
    #pragma unroll
    for (int g = 0; g < 2; g++)
        #pragma unroll
        for (int t = 0; t < NT; t++) acc[g][t] = (f32x4){0.f, 0.f, 0.f, 0.f};

    #pragma unroll
    for (int k0 = 0; k0 < K; k0 += 32) {
        bf16x8 a0v, a1v;
        if constexpr (ABF) {
            const unsigned short* A = (const unsigned short*)Av;
            a0v = *(const bf16x8*)(A + (size_t)r0 * K + k0 + kh * 8);
            a1v = *(const bf16x8*)(A + (size_t)r1 * K + k0 + kh * 8);
        } else {
            const float* A = (const float*)Av;
            float4 x0 = *(const float4*)(A + (size_t)r0 * K + k0 + kh * 8);
            float4 x1 = *(const float4*)(A + (size_t)r0 * K + k0 + kh * 8 + 4);
            float4 y0 = *(const float4*)(A + (size_t)r1 * K + k0 + kh * 8);
            float4 y1 = *(const float4*)(A + (size_t)r1 * K + k0 + kh * 8 + 4);
            union { bf16x8 v; unsigned short u[8]; } au, bu;
            au.u[0] = f2b(x0.x); au.u[1] = f2b(x0.y); au.u[2] = f2b(x0.z); au.u[3] = f2b(x0.w);
            au.u[4] = f2b(x1.x); au.u[5] = f2b(x1.y); au.u[6] = f2b(x1.z); au.u[7] = f2b(x1.w);
            bu.u[0] = f2b(y0.x); bu.u[1] = f2b(y0.y); bu.u[2] = f2b(y0.z); bu.u[3] = f2b(y0.w);
            bu.u[4] = f2b(y1.x); bu.u[5] = f2b(y1.y); bu.u[6] = f2b(y1.z); bu.u[7] = f2b(y1.w);
            a0v = au.v; a1v = bu.v;
        }
        #pragma unroll
        for (int t = 0; t < NT; t++) {
            bf16x8 bv = *(const bf16x8*)(WT + (size_t)(t * 16 + rl) * K + k0 + kh * 8);
            acc[0][t] = __builtin_amdgcn_mfma_f32_16x16x32_bf16(a0v, bv, acc[0][t], 0, 0, 0);
            acc[1][t] = __builtin_amdgcn_mfma_f32_16x16x32_bf16(a1v, bv, acc[1][t], 0, 0, 0);
        }
    }

    float asr[NT], adr[NT];
    #pragma unroll
    for (int t = 0; t < NT; t++) { asr[t] = a_src[t * 16 + rl]; adr[t] = a_dst[t * 16 + rl]; }

    #pragma unroll
    for (int rg = 0; rg < 2; rg++) {
        #pragma unroll
        for (int i = 0; i < 4; i++) {
            int r = wrow0 + rg * 16 + kh * 4 + i;
            bool ok = (r < M);
            float ps = 0.f, pd = 0.f;
            #pragma unroll
            for (int t = 0; t < NT; t++) {
                float v = acc[rg][t][i];
                ps += v * asr[t];
                pd += v * adr[t];
            }
            #pragma unroll
            for (int off = 1; off < 16; off <<= 1) {
                ps += __shfl_xor(ps, off);
                pd += __shfl_xor(pd, off);
            }
            if (ok && rl == 0) { al_s[r] = ps; al_d[r] = pd; }
            #pragma unroll
            for (int t = 0; t < NT; t++) {
                float v = acc[rg][t][i];
                float hi = __shfl_xor(v, 1);
                if (ok && !(rl & 1))
                    hb[(size_t)r * (N / 2) + (t * 16 + rl) / 2] = packb(v, hi);
            }
        }
    }
}

// ---------------- binned CSR build ----------------
// pass A: bin edges into NBUK buckets (x4 sub-buckets) of 512 dst-nodes each
__global__ void bin_kernel(const int* __restrict__ src, const int* __restrict__ dst,
                           int* __restrict__ bcur, uint2* __restrict__ bbuf, int ne) {
    int stride = gridDim.x * blockDim.x;
    for (int e = blockIdx.x * blockDim.x + threadIdx.x; e < ne; e += stride) {
        int d = dst[e];
        int bk = ((d >> 9) << 2) | (e & 3);
        int p = atomicAdd(&bcur[bk], 1);
        if (p < CAP4) bbuf[(size_t)bk * CAP4 + p] = make_uint2((unsigned)src[e], (unsigned)d);
    }
}

// exclusive scan of bucket totals (nb <= 256), single block
__global__ void bucket_scan_kernel(const int* __restrict__ bcur, int* __restrict__ bbase, int nb) {
    __shared__ int part[256];
    int t = threadIdx.x;
    int v = 0;
    if (t < nb) v = bcur[t * 4] + bcur[t * 4 + 1] + bcur[t * 4 + 2] + bcur[t * 4 + 3];
    part[t] = v;
    __syncthreads();
    for (int off = 1; off < 256; off <<= 1) {
        int u = (t >= off) ? part[t - off] : 0;
        __syncthreads();
        part[t] += u;
        __syncthreads();
    }
    if (t < nb) bbase[t] = part[t] - v;
}

// pass B: one block per bucket -> LDS histogram + scan -> rowptr + col (L2-local window)
__global__ __launch_bounds__(256) void csr_bucket_kernel(const uint2* __restrict__ bbuf,
                                                         const int* __restrict__ bcur,
                                                         const int* __restrict__ bbase,
                                                         int* __restrict__ rowptr,
                                                         int* __restrict__ col, int nn) {
    __shared__ int deg[512];
    __shared__ int part[256];
    __shared__ int cur[512];
    const int b = blockIdx.x, t = threadIdx.x;
    const int n0 = b * 512;
    const int nloc = min(512, nn - n0);
    const int base = bbase[b];
    deg[t] = 0; deg[t + 256] = 0;
    __syncthreads();
    // count
    for (int sub = 0; sub < 4; sub++) {
        int cnt = min(bcur[b * 4 + sub], CAP4);
        const uint2* p = bbuf + (size_t)(b * 4 + sub) * CAP4;
        for (int i = t; i < cnt; i += 256) {
            uint2 e = p[i];
            atomicAdd(&deg[(int)e.y - n0], 1);
        }
    }
    __syncthreads();
    // exclusive scan over 512 (pairwise + 256-scan)
    int d0 = deg[2 * t], d1 = deg[2 * t + 1];
    int s = d0 + d1;
    part[t] = s;
    __syncthreads();
    for (int off = 1; off < 256; off <<= 1) {
        int u = (t >= off) ? part[t - off] : 0;
        __syncthreads();
        part[t] += u;
        __syncthreads();
    }
    int ex = part[t] - s;
    cur[2 * t] = ex;
    cur[2 * t + 1] = ex + d0;
    if (2 * t < nloc) rowptr[n0 + 2 * t] = base + ex;
    if (2 * t + 1 < nloc) rowptr[n0 + 2 * t + 1] = base + ex + d0;
    if (t == 0 && n0 + nloc == nn) rowptr[nn] = base + part[255];
    __syncthreads();
    // place
    for (int sub = 0; sub < 4; sub++) {
        int cnt = min(bcur[b * 4 + sub], CAP4);
        const uint2* p = bbuf + (size_t)(b * 4 + sub) * CAP4;
        for (int i = t; i < cnt; i += 256) {
            uint2 e = p[i];
            int pos = atomicAdd(&cur[(int)e.y - n0], 1);
            col[base + pos] = (int)e.x;
        }
    }
}

// ---------------- graph boundaries via binary search (batch sorted) ----------------
__global__ void brow_kernel(const int* __restrict__ batch, int* __restrict__ brow, int n, int nb) {
    int g = blockIdx.x * blockDim.x + threadIdx.x;
    if (g > nb) return;
    int lo = 0, hi = n;
    while (lo < hi) {
        int mid = (lo + hi) >> 1;
        if (batch[mid] < g) lo = mid + 1; else hi = mid;
    }
    brow[g] = lo;
}

// ---------------- GAT aggregate, D=128: one edge per wave-pass; bf16 in, bf16 out ------
__global__ void gat_gather128_kernel(const int* __restrict__ rowptr, const int* __restrict__ col,
                                     const float* __restrict__ al_s, const float* __restrict__ al_d,
                                     const unsigned* __restrict__ hb,
                                     const float* __restrict__ bias,
                                     unsigned* __restrict__ outb, int n) {
    int node = blockIdx.x * 4 + (threadIdx.x >> 6);
    int lane = threadIdx.x & 63;
    if (node >= n) return;
    const int beg = rowptr[node], end = rowptr[node + 1];
    const float ald = al_d[node];
    const float e_self = leaky(al_s[node] + ald);

    float acc0 = 0.f, acc1 = 0.f, dsum = 0.f;
    for (int base = beg; base < end; base += 64) {
        int i = base + lane;
        float w = 0.f; int s = 0;
        if (i < end) {
            s = col[i];
            w = expf(leaky(al_s[s] + ald));   // no max shift: |e| small, f32-safe
        }
        dsum += w;
        int cnt = min(64, end - base);
        int j = 0;
        for (; j + 8 <= cnt; j += 8) {
            float wj[8]; int sj[8];
            #pragma unroll
            for (int u = 0; u < 8; u++) { wj[u] = __shfl(w, j + u); sj[u] = __shfl(s, j + u); }
            unsigned v[8];
            #pragma unroll
            for (int u = 0; u < 8; u++) v[u] = hb[(size_t)sj[u] * 64 + lane];
            #pragma unroll
            for (int u = 0; u < 8; u++) {
                acc0 += wj[u] * b2f_lo(v[u]);
                acc1 += wj[u] * b2f_hi(v[u]);
            }
        }
        for (; j < cnt; j++) {
            float wj = __shfl(w, j);
            int sj = __shfl(s, j);
            unsigned v = hb[(size_t)sj * 64 + lane];
            acc0 += wj * b2f_lo(v);
            acc1 += wj * b2f_hi(v);
        }
    }
    #pragma unroll
    for (int off = 32; off > 0; off >>= 1) dsum += __shfl_xor(dsum, off);

    float wself = expf(e_self);
    dsum += wself;
    float inv = 1.f / dsum;
    unsigned sv = hb[(size_t)node * 64 + lane];
    int c0 = 2 * lane, c1 = c0 + 1;
    float o0 = bias[c0] + (acc0 + wself * b2f_lo(sv)) * inv;
    float o1 = bias[c1] + (acc1 + wself * b2f_hi(sv)) * inv;
    outb[(size_t)node * 64 + lane] = packb(o0, o1);
}

// ---------------- GAT aggregate, D=64: TWO edges per wave-pass; bf16 in, f32 out ------
__global__ void gat_gather64_kernel(const int* __restrict__ rowptr, const int* __restrict__ col,
                                    const float* __restrict__ al_s, const float* __restrict__ al_d,
                                    const unsigned* __restrict__ hb,
                                    const float* __restrict__ bias,
                                    float* __restrict__ out, int n) {
    int node = blockIdx.x * 4 + (threadIdx.x >> 6);
    int lane = threadIdx.x & 63;
    if (node >= n) return;
    const int sl = lane & 31, half = lane >> 5;
    const int beg = rowptr[node], end = rowptr[node + 1];
    const float ald = al_d[node];
    const float e_self = leaky(al_s[node] + ald);

    float acc0 = 0.f, acc1 = 0.f, dsum = 0.f;
    for (int base = beg; base < end; base += 64) {
        int i = base + lane;
        float w = 0.f; int s = 0;
        if (i < end) {
            s = col[i];
            w = expf(leaky(al_s[s] + ald));
        }
        dsum += w;
        int cnt = min(64, end - base);
        int j = 0;
        for (; j + 8 <= cnt; j += 8) {
            float wj[4]; int sj[4];
            #pragma unroll
            for (int u = 0; u < 4; u++) {
                int idx = j + 2 * u + half;
                wj[u] = __shfl(w, idx);
                sj[u] = __shfl(s, idx);
            }
            unsigned v[4];
            #pragma unroll
            for (int u = 0; u < 4; u++) v[u] = hb[(size_t)sj[u] * 32 + sl];
            #pragma unroll
            for (int u = 0; u < 4; u++) {
                acc0 += wj[u] * b2f_lo(v[u]);
                acc1 += wj[u] * b2f_hi(v[u]);
            }
        }
        for (; j < cnt; j += 2) {
            int idx = j + half;
            float wj = (idx < cnt) ? __shfl(w, idx) : 0.f;
            int sj = __shfl(s, idx < cnt ? idx : 0);
            unsigned v = hb[(size_t)sj * 32 + sl];
            acc0 += wj * b2f_lo(v);
            acc1 += wj * b2f_hi(v);
        }
    }
    acc0 += __shfl_xor(acc0, 32);
    acc1 += __shfl_xor(acc1, 32);
    #pragma unroll
    for (int off = 32; off > 0; off >>= 1) dsum += __shfl_xor(dsum, off);

    float wself = expf(e_self);
    dsum += wself;
    float inv = 1.f / dsum;
    if (half == 0) {
        unsigned sv = hb[(size_t)node * 32 + sl];
        float* op = out + (size_t)node * 64;
        int c0 = 2 * sl;
        float o0 = bias[c0] + (acc0 + wself * b2f_lo(sv)) * inv;
        float o1 = bias[c0 + 1] + (acc1 + wself * b2f_hi(sv)) * inv;
        *(float2*)(op + c0) = make_float2(o0, o1);
    }
}

// ---------------- segmented mean pool: one block per graph ----------------
__global__ void pool_seg_kernel(const float* __restrict__ x, const int* __restrict__ brow,
                                float* __restrict__ pooled) {
    __shared__ float red[4][64];
    int g = blockIdx.x;
    int lane = threadIdx.x & 63, w = threadIdx.x >> 6;
    int beg = brow[g], end = brow[g + 1];
    float acc = 0.f;
    for (int n = beg + w; n < end; n += 4)
        acc += x[(size_t)n * 64 + lane];
    red[w][lane] = acc;
    __syncthreads();
    if (w == 0) {
        float s = red[0][lane] + red[1][lane] + red[2][lane] + red[3][lane];
        float cnt = (float)(end - beg);
        pooled[(size_t)g * 64 + lane] = s / fmaxf(cnt, 1.f);
    }
}

// ---------------- final: sigmoid((xs+xt)@lin_w + lin_b) ----------------
__global__ void final_kernel(const float* __restrict__ ps, const float* __restrict__ pt,
                             const float* __restrict__ lw, const float* __restrict__ lb,
                             float* __restrict__ out) {
    int g = blockIdx.x;
    int c = threadIdx.x;
    if (c >= 27) return;
    float acc = lb[c];
    #pragma unroll 8
    for (int k = 0; k < 64; k++) {
        float xv = ps[g * 64 + k] + pt[g * 64 + k];
        acc += xv * lw[k * 27 + c];
    }
    out[g * 27 + c] = 1.f / (1.f + expf(-acc));
}

static void build_csr(const int* src, const int* dst, int* rowptr, int* bcur, int* bbase,
                      uint2* bbuf, int* col, hipStream_t stream) {
    hipMemsetAsync(bcur, 0, NBUK * 4 * sizeof(int), stream);
    bin_kernel<<<1024, 256, 0, stream>>>(src, dst, bcur, bbuf, EE);
    bucket_scan_kernel<<<1, 256, 0, stream>>>(bcur, bbase, NBUK);
    csr_bucket_kernel<<<NBUK, 256, 0, stream>>>(bbuf, bcur, bbase, rowptr, col, NN);
}

// ---------------- one branch: conv1(128) -> conv2(64) -> pool ----------------
static void run_branch(const float* x,
                       const float* W1, const float* as1, const float* ad1, const float* b1,
                       const float* W2, const float* as2, const float* ad2, const float* b2,
                       const int* rowptr, const int* col, const int* batch,
                       unsigned* hb, unsigned* out1b, float* out2,
                       float* al_s, float* al_d, unsigned short* WT,
                       int* brow, float* pooled, hipStream_t stream) {
    int gemm_blocks = (NN + 127) / 128;
    int gather_blocks = (NN + 3) / 4;

    wt_kernel<<<(256 * 128 + 255) / 256, 256, 0, stream>>>(W1, WT, 256, 128);
    gemm_fused_kernel<256, 128, false><<<gemm_blocks, 256, 0, stream>>>(
        x, WT, as1, ad1, hb, al_s, al_d, NN);
    gat_gather128_kernel<<<gather_blocks, 256, 0, stream>>>(
        rowptr, col, al_s, al_d, hb, b1, out1b, NN);

    wt_kernel<<<(128 * 64 + 255) / 256, 256, 0, stream>>>(W2, WT, 128, 64);
    gemm_fused_kernel<128, 64, true><<<gemm_blocks, 256, 0, stream>>>(
        out1b, WT, as2, ad2, hb, al_s, al_d, NN);
    gat_gather64_kernel<<<gather_blocks, 256, 0, stream>>>(
        rowptr, col, al_s, al_d, hb, b2, out2, NN);

    brow_kernel<<<(BB + 1 + 255) / 256, 256, 0, stream>>>(batch, brow, NN, BB);
    pool_seg_kernel<<<BB, 256, 0, stream>>>(out2, brow, pooled);
}

extern "C" void kernel_launch(void* const* d_in, const int* in_sizes, int n_in,
                              void* d_out, int out_size, void* d_ws, size_t ws_size,
                              hipStream_t stream) {
    const float* x_s = (const float*)d_in[0];
    const float* x_t = (const float*)d_in[1];
    const int* ei_s = (const int*)d_in[2];
    const int* ei_t = (const int*)d_in[3];
    const int* xs_batch = (const int*)d_in[4];
    const int* xt_batch = (const int*)d_in[5];
    const float* W_s1 = (const float*)d_in[6];
    const float* a_src_s1 = (const float*)d_in[7];
    const float* a_dst_s1 = (const float*)d_in[8];
    const float* b_s1 = (const float*)d_in[9];
    const float* W_s2 = (const float*)d_in[10];
    const float* a_src_s2 = (const float*)d_in[11];
    const float* a_dst_s2 = (const float*)d_in[12];
    const float* b_s2 = (const float*)d_in[13];
    const float* W_t1 = (const float*)d_in[14];
    const float* a_src_t1 = (const float*)d_in[15];
    const float* a_dst_t1 = (const float*)d_in[16];
    const float* b_t1 = (const float*)d_in[17];
    const float* W_t2 = (const float*)d_in[18];
    const float* a_src_t2 = (const float*)d_in[19];
    const float* a_dst_t2 = (const float*)d_in[20];
    const float* b_t2 = (const float*)d_in[21];
    const float* lin_w = (const float*)d_in[22];
    const float* lin_b = (const float*)d_in[23];
    float* out = (float*)d_out;

    // workspace carve-up (bbuf first for 8B alignment)
    uint2* bbuf = (uint2*)d_ws;                          // NBUK*4*CAP4 pairs (~16 MB)
    unsigned* hb = (unsigned*)(bbuf + (size_t)NBUK * 4 * CAP4);  // NN*64 dwords
    unsigned* out1b = hb + (size_t)NN * 64;              // NN*64 dwords
    float* out2 = (float*)(out1b + (size_t)NN * 64);     // NN*64 f32
    float* al_s = out2 + (size_t)NN * 64;                // NN
    float* al_d = al_s + NN;                             // NN
    float* pooled_s = al_d + NN;                         // BB*64
    float* pooled_t = pooled_s + (size_t)BB * 64;        // BB*64
    int* col = (int*)(pooled_t + (size_t)BB * 64);       // EE
    unsigned short* WT = (unsigned short*)(col + EE);    // 32768 bf16
    int* rowptr = (int*)(WT + 32768);                    // NN+1
    int* bcur = rowptr + NN + 1;                         // NBUK*4
    int* bbase = bcur + NBUK * 4;                        // NBUK
    int* brow = bbase + NBUK;                            // BB+1

    const int* src_s = ei_s;
    const int* dst_s = ei_s + EE;
    const int* src_t = ei_t;
    const int* dst_t = ei_t + EE;

    // ----- branch s -----
    build_csr(src_s, dst_s, rowptr, bcur, bbase, bbuf, col, stream);
    run_branch(x_s, W_s1, a_src_s1, a_dst_s1, b_s1, W_s2, a_src_s2, a_dst_s2, b_s2,
               rowptr, col, xs_batch, hb, out1b, out2, al_s, al_d, WT, brow, pooled_s, stream);

    // ----- branch t -----
    build_csr(src_t, dst_t, rowptr, bcur, bbase, bbuf, col, stream);
    run_branch(x_t, W_t1, a_src_t1, a_dst_t1, b_t1, W_t2, a_src_t2, a_dst_t2, b_t2,
               rowptr, col, xt_batch, hb, out1b, out2, al_s, al_d, WT, brow, pooled_t, stream);

    // ----- head -----
    final_kernel<<<BB, 32, 0, stream>>>(pooled_s, pooled_t, lin_w, lin_b, out);
}

// Round 9
// 700.468 us; speedup vs baseline: 1.8408x; 1.8408x over previous
//
#include <hip/hip_runtime.h>
#include <hip/hip_bf16.h>
#include <math.h>

#define NEG_SLOPE 0.2f

static const int NN = 100000;   // nodes per branch
static const int EE = 1600000;  // edges per branch
static const int BB = 512;      // graphs
static const int DD = 256;      // input dim
static const int NBUK = (NN + 511) / 512;     // 196 buckets of 512 nodes
static const int CHUNK = 4096;                // edges per bin-sort block
static const int NBLK = (EE + CHUNK - 1) / CHUNK;  // 391 chunks
static const int HROW = NBUK + 1;             // 197: scanned hist row stride

typedef __attribute__((ext_vector_type(8))) short bf16x8;
typedef __attribute__((ext_vector_type(4))) float f32x4;

__device__ __forceinline__ float leaky(float x) { return x >= 0.f ? x : NEG_SLOPE * x; }

__device__ __forceinline__ unsigned short f2b(float f) {
    __hip_bfloat16 h = __float2bfloat16(f);   // RNE
    return *reinterpret_cast<unsigned short*>(&h);
}
__device__ __forceinline__ float b2f_lo(unsigned v) { return __uint_as_float(v << 16); }
__device__ __forceinline__ float b2f_hi(unsigned v) { return __uint_as_float(v & 0xFFFF0000u); }
__device__ __forceinline__ unsigned packb(float a, float b) {
    return (unsigned)f2b(a) | ((unsigned)f2b(b) << 16);
}

// ---------------- W^T cast: WT[n][k] = bf16(W[k][n]) ----------------
__global__ void wt_kernel(const float* __restrict__ W, unsigned short* __restrict__ WT,
                          int K, int N) {
    int idx = blockIdx.x * blockDim.x + threadIdx.x;
    if (idx >= K * N) return;
    int n = idx / K, k = idx - n * K;
    WT[idx] = f2b(W[(size_t)k * N + n]);
}

// ---- fused MFMA GEMM: hb = packed-bf16(bf16(A)@bf16(W)); al_s/al_d = h·a_src / h·a_dst.
//      32 rows/wave, 128 rows/block. ABF: A is bf16 (ushort) instead of f32. ----
template <int K, int N, bool ABF>
__global__ __launch_bounds__(256, 2) void gemm_fused_kernel(const void* __restrict__ Av,
                                                            const unsigned short* __restrict__ WT,
                                                            const float* __restrict__ a_src,
                                                            const float* __restrict__ a_dst,
                                                            unsigned* __restrict__ hb,
                                                            float* __restrict__ al_s,
                                                            float* __restrict__ al_d, int M) {
    constexpr int NT = N / 16;
    const int l = threadIdx.x & 63;
    const int w = threadIdx.x >> 6;
    const int rl = l & 15;
    const int kh = l >> 4;
    const int wrow0 = blockIdx.x * 128 + w * 32;
    const int r0 = min(wrow0 + rl, M - 1);
    const int r1 = min(wrow0 + 16 + rl, M - 1);

    f32x4 acc[2][NT];
    #pragma unroll
    for (int g = 0; g < 2; g++)
        #pragma unroll
        for (int t = 0; t < NT; t++) acc[g][t] = (f32x4){0.f, 0.f, 0.f, 0.f};

    #pragma unroll
    for (int k0 = 0; k0 < K; k0 += 32) {
        bf16x8 a0v, a1v;
        if constexpr (ABF) {
            const unsigned short* A = (const unsigned short*)Av;
            a0v = *(const bf16x8*)(A + (size_t)r0 * K + k0 + kh * 8);
            a1v = *(const bf16x8*)(A + (size_t)r1 * K + k0 + kh * 8);
        } else {
            const float* A = (const float*)Av;
            float4 x0 = *(const float4*)(A + (size_t)r0 * K + k0 + kh * 8);
            float4 x1 = *(const float4*)(A + (size_t)r0 * K + k0 + kh * 8 + 4);
            float4 y0 = *(const float4*)(A + (size_t)r1 * K + k0 + kh * 8);
            float4 y1 = *(const float4*)(A + (size_t)r1 * K + k0 + kh * 8 + 4);
            union { bf16x8 v; unsigned short u[8]; } au, bu;
            au.u[0] = f2b(x0.x); au.u[1] = f2b(x0.y); au.u[2] = f2b(x0.z); au.u[3] = f2b(x0.w);
            au.u[4] = f2b(x1.x); au.u[5] = f2b(x1.y); au.u[6] = f2b(x1.z); au.u[7] = f2b(x1.w);
            bu.u[0] = f2b(y0.x); bu.u[1] = f2b(y0.y); bu.u[2] = f2b(y0.z); bu.u[3] = f2b(y0.w);
            bu.u[4] = f2b(y1.x); bu.u[5] = f2b(y1.y); bu.u[6] = f2b(y1.z); bu.u[7] = f2b(y1.w);
            a0v = au.v; a1v = bu.v;
        }
        #pragma unroll
        for (int t = 0; t < NT; t++) {
            bf16x8 bv = *(const bf16x8*)(WT + (size_t)(t * 16 + rl) * K + k0 + kh * 8);
            acc[0][t] = __builtin_amdgcn_mfma_f32_16x16x32_bf16(a0v, bv, acc[0][t], 0, 0, 0);
            acc[1][t] = __builtin_amdgcn_mfma_f32_16x16x32_bf16(a1v, bv, acc[1][t], 0, 0, 0);
        }
    }

    float asr[NT], adr[NT];
    #pragma unroll
    for (int t = 0; t < NT; t++) { asr[t] = a_src[t * 16 + rl]; adr[t] = a_dst[t * 16 + rl]; }

    #pragma unroll
    for (int rg = 0; rg < 2; rg++) {
        #pragma unroll
        for (int i = 0; i < 4; i++) {
            int r = wrow0 + rg * 16 + kh * 4 + i;
            bool ok = (r < M);
            float ps = 0.f, pd = 0.f;
            #pragma unroll
            for (int t = 0; t < NT; t++) {
                float v = acc[rg][t][i];
                ps += v * asr[t];
                pd += v * adr[t];
            }
            #pragma unroll
            for (int off = 1; off < 16; off <<= 1) {
                ps += __shfl_xor(ps, off);
                pd += __shfl_xor(pd, off);
            }
            if (ok && rl == 0) { al_s[r] = ps; al_d[r] = pd; }
            #pragma unroll
            for (int t = 0; t < NT; t++) {
                float v = acc[rg][t][i];
                float hi = __shfl_xor(v, 1);
                if (ok && !(rl & 1))
                    hb[(size_t)r * (N / 2) + (t * 16 + rl) / 2] = packb(v, hi);
            }
        }
    }
}

// ---------------- binned CSR build, atomic-free pass A ----------------
// Each block bucket-sorts its 4096-edge chunk in LDS, streams it out contiguously,
// and stores its per-bucket exclusive-scan row (197 ints).
__global__ __launch_bounds__(256) void bin_sort_kernel(const int* __restrict__ src,
                                                       const int* __restrict__ dst,
                                                       uint2* __restrict__ region,
                                                       int* __restrict__ shist, int ne) {
    __shared__ int hist[256];
    __shared__ int part[256];
    __shared__ int cur[256];
    __shared__ uint2 lbuf[CHUNK];
    const int b = blockIdx.x, t = threadIdx.x;
    const int base = b * CHUNK;
    const int cnt = min(CHUNK, ne - base);
    hist[t] = 0;
    __syncthreads();
    unsigned es[16], ed[16];
    #pragma unroll
    for (int i = 0; i < 16; i++) {
        int li = i * 256 + t;
        if (li < cnt) {
            es[i] = (unsigned)src[base + li];
            ed[i] = (unsigned)dst[base + li];
            atomicAdd(&hist[ed[i] >> 9], 1);
        }
    }
    __syncthreads();
    int v = hist[t];
    part[t] = v;
    __syncthreads();
    for (int off = 1; off < 256; off <<= 1) {
        int u = (t >= off) ? part[t - off] : 0;
        __syncthreads();
        part[t] += u;
        __syncthreads();
    }
    int ex = part[t] - v;
    cur[t] = ex;
    if (t < NBUK) shist[b * HROW + t] = ex;
    if (t == 0) shist[b * HROW + NBUK] = cnt;
    __syncthreads();
    #pragma unroll
    for (int i = 0; i < 16; i++) {
        int li = i * 256 + t;
        if (li < cnt) {
            int slot = atomicAdd(&cur[ed[i] >> 9], 1);
            lbuf[slot] = make_uint2(es[i], ed[i]);
        }
    }
    __syncthreads();
    for (int i = t; i < cnt; i += 256) region[base + i] = lbuf[i];
}

// per-bucket totals + exclusive scan -> bbase (one block, NBUK <= 256)
__global__ void bucket_base_kernel(const int* __restrict__ shist, int* __restrict__ bbase,
                                   int nb, int nblk) {
    __shared__ int part[256];
    int t = threadIdx.x;
    int tot = 0;
    if (t < nb) {
        for (int b = 0; b < nblk; b++)
            tot += shist[b * HROW + t + 1] - shist[b * HROW + t];
    }
    part[t] = tot;
    __syncthreads();
    for (int off = 1; off < 256; off <<= 1) {
        int u = (t >= off) ? part[t - off] : 0;
        __syncthreads();
        part[t] += u;
        __syncthreads();
    }
    if (t < nb) bbase[t] = part[t] - tot;
}

// pass B: one block per bucket -> LDS histogram + scan -> rowptr + col (L2-local window)
__global__ __launch_bounds__(256) void csr_bucket_kernel(const uint2* __restrict__ region,
                                                         const int* __restrict__ shist,
                                                         const int* __restrict__ bbase,
                                                         int* __restrict__ rowptr,
                                                         int* __restrict__ col, int nn, int nblk) {
    __shared__ int deg[512];
    __shared__ int part[256];
    __shared__ int cur[512];
    const int k = blockIdx.x, t = threadIdx.x;
    const int n0 = k * 512;
    const int nloc = min(512, nn - n0);
    const int base = bbase[k];
    deg[t] = 0; deg[t + 256] = 0;
    __syncthreads();
    // count
    for (int b = t; b < nblk; b += 256) {
        int s0 = shist[b * HROW + k], s1 = shist[b * HROW + k + 1];
        for (int i = s0; i < s1; i++) {
            uint2 e = region[(size_t)b * CHUNK + i];
            atomicAdd(&deg[(int)e.y - n0], 1);
        }
    }
    __syncthreads();
    // exclusive scan over 512 (pairwise + 256-scan)
    int d0 = deg[2 * t], d1 = deg[2 * t + 1];
    int s = d0 + d1;
    part[t] = s;
    __syncthreads();
    for (int off = 1; off < 256; off <<= 1) {
        int u = (t >= off) ? part[t - off] : 0;
        __syncthreads();
        part[t] += u;
        __syncthreads();
    }
    int ex = part[t] - s;
    cur[2 * t] = ex;
    cur[2 * t + 1] = ex + d0;
    if (2 * t < nloc) rowptr[n0 + 2 * t] = base + ex;
    if (2 * t + 1 < nloc) rowptr[n0 + 2 * t + 1] = base + ex + d0;
    if (t == 0 && n0 + nloc == nn) rowptr[nn] = base + part[255];
    __syncthreads();
    // place
    for (int b = t; b < nblk; b += 256) {
        int s0 = shist[b * HROW + k], s1 = shist[b * HROW + k + 1];
        for (int i = s0; i < s1; i++) {
            uint2 e = region[(size_t)b * CHUNK + i];
            int pos = atomicAdd(&cur[(int)e.y - n0], 1);
            col[base + pos] = (int)e.x;
        }
    }
}

// ---------------- graph boundaries via binary search (batch sorted) ----------------
__global__ void brow_kernel(const int* __restrict__ batch, int* __restrict__ brow, int n, int nb) {
    int g = blockIdx.x * blockDim.x + threadIdx.x;
    if (g > nb) return;
    int lo = 0, hi = n;
    while (lo < hi) {
        int mid = (lo + hi) >> 1;
        if (batch[mid] < g) lo = mid + 1; else hi = mid;
    }
    brow[g] = lo;
}

// ---------------- GAT aggregate, D=128: one edge per wave-pass; bf16 in, bf16 out ------
__global__ void gat_gather128_kernel(const int* __restrict__ rowptr, const int* __restrict__ col,
                                     const float* __restrict__ al_s, const float* __restrict__ al_d,
                                     const unsigned* __restrict__ hb,
                                     const float* __restrict__ bias,
                                     unsigned* __restrict__ outb, int n) {
    int node = blockIdx.x * 4 + (threadIdx.x >> 6);
    int lane = threadIdx.x & 63;
    if (node >= n) return;
    const int beg = rowptr[node], end = rowptr[node + 1];
    const float ald = al_d[node];
    const float e_self = leaky(al_s[node] + ald);

    float acc0 = 0.f, acc1 = 0.f, dsum = 0.f;
    for (int base = beg; base < end; base += 64) {
        int i = base + lane;
        float w = 0.f; int s = 0;
        if (i < end) {
            s = col[i];
            w = expf(leaky(al_s[s] + ald));   // no max shift: |e| small, f32-safe
        }
        dsum += w;
        int cnt = min(64, end - base);
        int j = 0;
        for (; j + 8 <= cnt; j += 8) {
            float wj[8]; int sj[8];
            #pragma unroll
            for (int u = 0; u < 8; u++) { wj[u] = __shfl(w, j + u); sj[u] = __shfl(s, j + u); }
            unsigned v[8];
            #pragma unroll
            for (int u = 0; u < 8; u++) v[u] = hb[(size_t)sj[u] * 64 + lane];
            #pragma unroll
            for (int u = 0; u < 8; u++) {
                acc0 += wj[u] * b2f_lo(v[u]);
                acc1 += wj[u] * b2f_hi(v[u]);
            }
        }
        for (; j < cnt; j++) {
            float wj = __shfl(w, j);
            int sj = __shfl(s, j);
            unsigned v = hb[(size_t)sj * 64 + lane];
            acc0 += wj * b2f_lo(v);
            acc1 += wj * b2f_hi(v);
        }
    }
    #pragma unroll
    for (int off = 32; off > 0; off >>= 1) dsum += __shfl_xor(dsum, off);

    float wself = expf(e_self);
    dsum += wself;
    float inv = 1.f / dsum;
    unsigned sv = hb[(size_t)node * 64 + lane];
    int c0 = 2 * lane, c1 = c0 + 1;
    float o0 = bias[c0] + (acc0 + wself * b2f_lo(sv)) * inv;
    float o1 = bias[c1] + (acc1 + wself * b2f_hi(sv)) * inv;
    outb[(size_t)node * 64 + lane] = packb(o0, o1);
}

// ---------------- GAT aggregate, D=64: TWO edges per wave-pass; bf16 in, f32 out ------
__global__ void gat_gather64_kernel(const int* __restrict__ rowptr, const int* __restrict__ col,
                                    const float* __restrict__ al_s, const float* __restrict__ al_d,
                                    const unsigned* __restrict__ hb,
                                    const float* __restrict__ bias,
                                    float* __restrict__ out, int n) {
    int node = blockIdx.x * 4 + (threadIdx.x >> 6);
    int lane = threadIdx.x & 63;
    if (node >= n) return;
    const int sl = lane & 31, half = lane >> 5;
    const int beg = rowptr[node], end = rowptr[node + 1];
    const float ald = al_d[node];
    const float e_self = leaky(al_s[node] + ald);

    float acc0 = 0.f, acc1 = 0.f, dsum = 0.f;
    for (int base = beg; base < end; base += 64) {
        int i = base + lane;
        float w = 0.f; int s = 0;
        if (i < end) {
            s = col[i];
            w = expf(leaky(al_s[s] + ald));
        }
        dsum += w;
        int cnt = min(64, end - base);
        int j = 0;
        for (; j + 8 <= cnt; j += 8) {
            float wj[4]; int sj[4];
            #pragma unroll
            for (int u = 0; u < 4; u++) {
                int idx = j + 2 * u + half;
                wj[u] = __shfl(w, idx);
                sj[u] = __shfl(s, idx);
            }
            unsigned v[4];
            #pragma unroll
            for (int u = 0; u < 4; u++) v[u] = hb[(size_t)sj[u] * 32 + sl];
            #pragma unroll
            for (int u = 0; u < 4; u++) {
                acc0 += wj[u] * b2f_lo(v[u]);
                acc1 += wj[u] * b2f_hi(v[u]);
            }
        }
        for (; j < cnt; j += 2) {
            int idx = j + half;
            float wj = (idx < cnt) ? __shfl(w, idx) : 0.f;
            int sj = __shfl(s, idx < cnt ? idx : 0);
            unsigned v = hb[(size_t)sj * 32 + sl];
            acc0 += wj * b2f_lo(v);
            acc1 += wj * b2f_hi(v);
        }
    }
    acc0 += __shfl_xor(acc0, 32);
    acc1 += __shfl_xor(acc1, 32);
    #pragma unroll
    for (int off = 32; off > 0; off >>= 1) dsum += __shfl_xor(dsum, off);

    float wself = expf(e_self);
    dsum += wself;
    float inv = 1.f / dsum;
    if (half == 0) {
        unsigned sv = hb[(size_t)node * 32 + sl];
        float* op = out + (size_t)node * 64;
        int c0 = 2 * sl;
        float o0 = bias[c0] + (acc0 + wself * b2f_lo(sv)) * inv;
        float o1 = bias[c0 + 1] + (acc1 + wself * b2f_hi(sv)) * inv;
        *(float2*)(op + c0) = make_float2(o0, o1);
    }
}

// ---------------- segmented mean pool: one block per graph ----------------
__global__ void pool_seg_kernel(const float* __restrict__ x, const int* __restrict__ brow,
                                float* __restrict__ pooled) {
    __shared__ float red[4][64];
    int g = blockIdx.x;
    int lane = threadIdx.x & 63, w = threadIdx.x >> 6;
    int beg = brow[g], end = brow[g + 1];
    float acc = 0.f;
    for (int n = beg + w; n < end; n += 4)
        acc += x[(size_t)n * 64 + lane];
    red[w][lane] = acc;
    __syncthreads();
    if (w == 0) {
        float s = red[0][lane] + red[1][lane] + red[2][lane] + red[3][lane];
        float cnt = (float)(end - beg);
        pooled[(size_t)g * 64 + lane] = s / fmaxf(cnt, 1.f);
    }
}

// ---------------- final: sigmoid((xs+xt)@lin_w + lin_b) ----------------
__global__ void final_kernel(const float* __restrict__ ps, const float* __restrict__ pt,
                             const float* __restrict__ lw, const float* __restrict__ lb,
                             float* __restrict__ out) {
    int g = blockIdx.x;
    int c = threadIdx.x;
    if (c >= 27) return;
    float acc = lb[c];
    #pragma unroll 8
    for (int k = 0; k < 64; k++) {
        float xv = ps[g * 64 + k] + pt[g * 64 + k];
        acc += xv * lw[k * 27 + c];
    }
    out[g * 27 + c] = 1.f / (1.f + expf(-acc));
}

static void build_csr(const int* src, const int* dst, int* rowptr, int* shist, int* bbase,
                      uint2* region, int* col, hipStream_t stream) {
    bin_sort_kernel<<<NBLK, 256, 0, stream>>>(src, dst, region, shist, EE);
    bucket_base_kernel<<<1, 256, 0, stream>>>(shist, bbase, NBUK, NBLK);
    csr_bucket_kernel<<<NBUK, 256, 0, stream>>>(region, shist, bbase, rowptr, col, NN, NBLK);
}

// ---------------- one branch: conv1(128) -> conv2(64) -> pool ----------------
static void run_branch(const float* x,
                       const float* W1, const float* as1, const float* ad1, const float* b1,
                       const float* W2, const float* as2, const float* ad2, const float* b2,
                       const int* rowptr, const int* col, const int* batch,
                       unsigned* hb, unsigned* out1b, float* out2,
                       float* al_s, float* al_d, unsigned short* WT,
                       int* brow, float* pooled, hipStream_t stream) {
    int gemm_blocks = (NN + 127) / 128;
    int gather_blocks = (NN + 3) / 4;

    wt_kernel<<<(256 * 128 + 255) / 256, 256, 0, stream>>>(W1, WT, 256, 128);
    gemm_fused_kernel<256, 128, false><<<gemm_blocks, 256, 0, stream>>>(
        x, WT, as1, ad1, hb, al_s, al_d, NN);
    gat_gather128_kernel<<<gather_blocks, 256, 0, stream>>>(
        rowptr, col, al_s, al_d, hb, b1, out1b, NN);

    wt_kernel<<<(128 * 64 + 255) / 256, 256, 0, stream>>>(W2, WT, 128, 64);
    gemm_fused_kernel<128, 64, true><<<gemm_blocks, 256, 0, stream>>>(
        out1b, WT, as2, ad2, hb, al_s, al_d, NN);
    gat_gather64_kernel<<<gather_blocks, 256, 0, stream>>>(
        rowptr, col, al_s, al_d, hb, b2, out2, NN);

    brow_kernel<<<(BB + 1 + 255) / 256, 256, 0, stream>>>(batch, brow, NN, BB);
    pool_seg_kernel<<<BB, 256, 0, stream>>>(out2, brow, pooled);
}

extern "C" void kernel_launch(void* const* d_in, const int* in_sizes, int n_in,
                              void* d_out, int out_size, void* d_ws, size_t ws_size,
                              hipStream_t stream) {
    const float* x_s = (const float*)d_in[0];
    const float* x_t = (const float*)d_in[1];
    const int* ei_s = (const int*)d_in[2];
    const int* ei_t = (const int*)d_in[3];
    const int* xs_batch = (const int*)d_in[4];
    const int* xt_batch = (const int*)d_in[5];
    const float* W_s1 = (const float*)d_in[6];
    const float* a_src_s1 = (const float*)d_in[7];
    const float* a_dst_s1 = (const float*)d_in[8];
    const float* b_s1 = (const float*)d_in[9];
    const float* W_s2 = (const float*)d_in[10];
    const float* a_src_s2 = (const float*)d_in[11];
    const float* a_dst_s2 = (const float*)d_in[12];
    const float* b_s2 = (const float*)d_in[13];
    const float* W_t1 = (const float*)d_in[14];
    const float* a_src_t1 = (const float*)d_in[15];
    const float* a_dst_t1 = (const float*)d_in[16];
    const float* b_t1 = (const float*)d_in[17];
    const float* W_t2 = (const float*)d_in[18];
    const float* a_src_t2 = (const float*)d_in[19];
    const float* a_dst_t2 = (const float*)d_in[20];
    const float* b_t2 = (const float*)d_in[21];
    const float* lin_w = (const float*)d_in[22];
    const float* lin_b = (const float*)d_in[23];
    float* out = (float*)d_out;

    // workspace carve-up (region first for 8B alignment)
    uint2* region = (uint2*)d_ws;                         // NBLK*CHUNK pairs (~12.8 MB)
    unsigned* hb = (unsigned*)(region + (size_t)NBLK * CHUNK);  // NN*64 dwords
    unsigned* out1b = hb + (size_t)NN * 64;               // NN*64 dwords
    float* out2 = (float*)(out1b + (size_t)NN * 64);      // NN*64 f32
    float* al_s = out2 + (size_t)NN * 64;                 // NN
    float* al_d = al_s + NN;                              // NN
    float* pooled_s = al_d + NN;                          // BB*64
    float* pooled_t = pooled_s + (size_t)BB * 64;         // BB*64
    int* col = (int*)(pooled_t + (size_t)BB * 64);        // EE
    unsigned short* WT = (unsigned short*)(col + EE);     // 32768 bf16
    int* rowptr = (int*)(WT + 32768);                     // NN+1
    int* shist = rowptr + NN + 1;                         // NBLK*HROW (~308 KB)
    int* bbase = shist + NBLK * HROW;                     // NBUK
    int* brow = bbase + NBUK;                             // BB+1

    const int* src_s = ei_s;
    const int* dst_s = ei_s + EE;
    const int* src_t = ei_t;
    const int* dst_t = ei_t + EE;

    // ----- branch s -----
    build_csr(src_s, dst_s, rowptr, shist, bbase, region, col, stream);
    run_branch(x_s, W_s1, a_src_s1, a_dst_s1, b_s1, W_s2, a_src_s2, a_dst_s2, b_s2,
               rowptr, col, xs_batch, hb, out1b, out2, al_s, al_d, WT, brow, pooled_s, stream);

    // ----- branch t -----
    build_csr(src_t, dst_t, rowptr, shist, bbase, region, col, stream);
    run_branch(x_t, W_t1, a_src_t1, a_dst_t1, b_t1, W_t2, a_src_t2, a_dst_t2, b_t2,
               rowptr, col, xt_batch, hb, out1b, out2, al_s, al_d, WT, brow, pooled_t, stream);

    // ----- head -----
    final_kernel<<<BB, 32, 0, stream>>>(pooled_s, pooled_t, lin_w, lin_b, out);
}

// Round 10
// 516.366 us; speedup vs baseline: 2.4970x; 1.3565x over previous
//
#include <hip/hip_runtime.h>
#include <hip/hip_bf16.h>
#include <math.h>

#define NEG_SLOPE 0.2f

static const int NN = 100000;    // nodes per branch
static const int EE = 1600000;   // edges per branch
static const int BB = 512;       // graphs
static const int NTOT = 2 * NN;  // 200000 combined nodes
static const int ETOT = 2 * EE;  // 3200000 combined edges
static const int NBUK = (NTOT + 511) / 512;        // 391 buckets of 512 nodes
static const int CHUNK = 4096;                     // edges per bin-sort block
static const int NBLK = (ETOT + CHUNK - 1) / CHUNK;  // 782 chunks
static const int GB = (NN + 63) / 64;              // 1563 gemm blocks per branch

typedef __attribute__((ext_vector_type(8))) short bf16x8;
typedef __attribute__((ext_vector_type(4))) float f32x4;

__device__ __forceinline__ float leaky(float x) { return x >= 0.f ? x : NEG_SLOPE * x; }

__device__ __forceinline__ unsigned short f2b(float f) {
    __hip_bfloat16 h = __float2bfloat16(f);   // RNE
    return *reinterpret_cast<unsigned short*>(&h);
}
__device__ __forceinline__ float b2f_lo(unsigned v) { return __uint_as_float(v << 16); }
__device__ __forceinline__ float b2f_hi(unsigned v) { return __uint_as_float(v & 0xFFFF0000u); }
__device__ __forceinline__ unsigned packb(float a, float b) {
    return (unsigned)f2b(a) | ((unsigned)f2b(b) << 16);
}

// ---------------- W^T cast for both branches: WT[br][n][k] = bf16(W_br[k][n]) ------
__global__ void wt2_kernel(const float* __restrict__ Ws, const float* __restrict__ Wt_,
                           unsigned short* __restrict__ WT, int K, int N) {
    int idx = blockIdx.x * blockDim.x + threadIdx.x;
    if (idx >= 2 * K * N) return;
    int br = idx >= K * N;
    int j = idx - br * K * N;
    int n = j / K, k = j - n * K;
    const float* W = br ? Wt_ : Ws;
    WT[idx] = f2b(W[(size_t)k * N + n]);
}

// ---- fused MFMA GEMM, both branches in one grid.
//      Block: 64 rows x N cols; wave (wm,wn): 32 rows x N/2 cols. acc = 2 x NT2 x f32x4.
//      Outputs: hb packed-bf16 h; al_s/al_d dots (combined across wn via LDS). ----
template <int K, int N, bool ABF>
__global__ __launch_bounds__(256, 3) void gemm_fused_kernel(
        const void* __restrict__ Av_s, const void* __restrict__ Av_t,
        const unsigned short* __restrict__ WT,   // [2][N][K]
        const float* __restrict__ as_s, const float* __restrict__ ad_s,
        const float* __restrict__ as_t, const float* __restrict__ ad_t,
        unsigned* __restrict__ hb, float* __restrict__ al_s, float* __restrict__ al_d,
        int nblk) {
    constexpr int NT2 = N / 32;      // 16-col tiles per wave (half of N)
    __shared__ float als0[64], ald0[64];
    const int bid = blockIdx.x;
    const int br = (bid >= nblk) ? 1 : 0;
    const int lb = bid - br * nblk;
    const int t = threadIdx.x;
    const int l = t & 63, w = t >> 6;
    const int wm = w >> 1, wn = w & 1;
    const int rl = l & 15, kh = l >> 4;
    const int row0 = lb * 64 + wm * 32;             // branch-local row base of this wave
    const int r0 = min(row0 + rl, NN - 1);
    const int r1 = min(row0 + 16 + rl, NN - 1);
    const void* Av = br ? Av_t : Av_s;
    const unsigned short* WTb = WT + (size_t)br * N * K;
    const float* asv = br ? as_t : as_s;
    const float* adv = br ? ad_t : ad_s;

    f32x4 acc[2][NT2];
    #pragma unroll
    for (int g = 0; g < 2; g++)
        #pragma unroll
        for (int q = 0; q < NT2; q++) acc[g][q] = (f32x4){0.f, 0.f, 0.f, 0.f};

    #pragma unroll
    for (int k0 = 0; k0 < K; k0 += 32) {
        bf16x8 a0v, a1v;
        if constexpr (ABF) {
            const unsigned short* A = (const unsigned short*)Av;
            a0v = *(const bf16x8*)(A + (size_t)r0 * K + k0 + kh * 8);
            a1v = *(const bf16x8*)(A + (size_t)r1 * K + k0 + kh * 8);
        } else {
            const float* A = (const float*)Av;
            float4 x0 = *(const float4*)(A + (size_t)r0 * K + k0 + kh * 8);
            float4 x1 = *(const float4*)(A + (size_t)r0 * K + k0 + kh * 8 + 4);
            float4 y0 = *(const float4*)(A + (size_t)r1 * K + k0 + kh * 8);
            float4 y1 = *(const float4*)(A + (size_t)r1 * K + k0 + kh * 8 + 4);
            union { bf16x8 v; unsigned short u[8]; } au, bu;
            au.u[0] = f2b(x0.x); au.u[1] = f2b(x0.y); au.u[2] = f2b(x0.z); au.u[3] = f2b(x0.w);
            au.u[4] = f2b(x1.x); au.u[5] = f2b(x1.y); au.u[6] = f2b(x1.z); au.u[7] = f2b(x1.w);
            bu.u[0] = f2b(y0.x); bu.u[1] = f2b(y0.y); bu.u[2] = f2b(y0.z); bu.u[3] = f2b(y0.w);
            bu.u[4] = f2b(y1.x); bu.u[5] = f2b(y1.y); bu.u[6] = f2b(y1.z); bu.u[7] = f2b(y1.w);
            a0v = au.v; a1v = bu.v;
        }
        #pragma unroll
        for (int q = 0; q < NT2; q++) {
            int c = wn * (N / 2) + q * 16 + rl;
            bf16x8 bv = *(const bf16x8*)(WTb + (size_t)c * K + k0 + kh * 8);
            acc[0][q] = __builtin_amdgcn_mfma_f32_16x16x32_bf16(a0v, bv, acc[0][q], 0, 0, 0);
            acc[1][q] = __builtin_amdgcn_mfma_f32_16x16x32_bf16(a1v, bv, acc[1][q], 0, 0, 0);
        }
    }

    float asr[NT2], adr[NT2];
    #pragma unroll
    for (int q = 0; q < NT2; q++) {
        int c = wn * (N / 2) + q * 16 + rl;
        asr[q] = asv[c];
        adr[q] = adv[c];
    }

    // per-(rg,i) partial al dots, reduced over this wave's 16 rl lanes
    float psA[2][4], pdA[2][4];
    #pragma unroll
    for (int rg = 0; rg < 2; rg++) {
        #pragma unroll
        for (int i = 0; i < 4; i++) {
            float ps = 0.f, pd = 0.f;
            #pragma unroll
            for (int q = 0; q < NT2; q++) {
                float v = acc[rg][q][i];
                ps += v * asr[q];
                pd += v * adr[q];
            }
            #pragma unroll
            for (int off = 1; off < 16; off <<= 1) {
                ps += __shfl_xor(ps, off);
                pd += __shfl_xor(pd, off);
            }
            psA[rg][i] = ps;
            pdA[rg][i] = pd;
        }
    }
    // combine wn halves via LDS
    if (wn == 0 && rl == 0) {
        #pragma unroll
        for (int rg = 0; rg < 2; rg++)
            #pragma unroll
            for (int i = 0; i < 4; i++) {
                int rloc = wm * 32 + rg * 16 + kh * 4 + i;
                als0[rloc] = psA[rg][i];
                ald0[rloc] = pdA[rg][i];
            }
    }
    __syncthreads();
    if (wn == 1 && rl == 0) {
        #pragma unroll
        for (int rg = 0; rg < 2; rg++)
            #pragma unroll
            for (int i = 0; i < 4; i++) {
                int rloc = wm * 32 + rg * 16 + kh * 4 + i;
                int rlocal = lb * 64 + rloc;
                if (rlocal < NN) {
                    int g = br * NN + rlocal;
                    al_s[g] = psA[rg][i] + als0[rloc];
                    al_d[g] = pdA[rg][i] + ald0[rloc];
                }
            }
    }
    // hb packed-bf16 writes (each wave owns its N/2 cols)
    #pragma unroll
    for (int rg = 0; rg < 2; rg++) {
        #pragma unroll
        for (int i = 0; i < 4; i++) {
            int rlocal = lb * 64 + wm * 32 + rg * 16 + kh * 4 + i;
            bool ok = (rlocal < NN);
            int g = br * NN + rlocal;
            #pragma unroll
            for (int q = 0; q < NT2; q++) {
                float v = acc[rg][q][i];
                float hi = __shfl_xor(v, 1);
                if (ok && !(rl & 1)) {
                    int c = wn * (N / 2) + q * 16 + rl;
                    hb[(size_t)g * (N / 2) + (c >> 1)] = packb(v, hi);
                }
            }
        }
    }
}

// ---------------- binned CSR build (combined graph), atomic-free pass A ----------------
// Each block bucket-sorts its 4096-edge chunk in LDS (512-bucket hist) and streams it out.
// shist layout: [bucket k][chunk b], stride NBLK.
__global__ __launch_bounds__(256) void bin_sort_kernel(const int* __restrict__ src_s,
                                                       const int* __restrict__ dst_s,
                                                       const int* __restrict__ src_t,
                                                       const int* __restrict__ dst_t,
                                                       uint2* __restrict__ region,
                                                       int* __restrict__ shist) {
    __shared__ int hist[512];
    __shared__ int part[256];
    __shared__ int cur[512];
    __shared__ uint2 lbuf[CHUNK];
    const int b = blockIdx.x, t = threadIdx.x;
    const int base = b * CHUNK;
    const int cnt = min(CHUNK, ETOT - base);
    hist[t] = 0; hist[t + 256] = 0;
    __syncthreads();
    unsigned es[16], ed[16];
    #pragma unroll
    for (int i = 0; i < 16; i++) {
        int li = i * 256 + t;
        if (li < cnt) {
            int e = base + li;
            if (e < EE) {
                es[i] = (unsigned)src_s[e];
                ed[i] = (unsigned)dst_s[e];
            } else {
                es[i] = (unsigned)src_t[e - EE] + NN;
                ed[i] = (unsigned)dst_t[e - EE] + NN;
            }
            atomicAdd(&hist[ed[i] >> 9], 1);
        }
    }
    __syncthreads();
    // exclusive scan over 512 (pairwise + 256-scan)
    int d0 = hist[2 * t], d1 = hist[2 * t + 1];
    int s = d0 + d1;
    part[t] = s;
    __syncthreads();
    for (int off = 1; off < 256; off <<= 1) {
        int u = (t >= off) ? part[t - off] : 0;
        __syncthreads();
        part[t] += u;
        __syncthreads();
    }
    int ex = part[t] - s;
    cur[2 * t] = ex;
    cur[2 * t + 1] = ex + d0;
    if (2 * t < NBUK + 1) shist[(2 * t) * NBLK + b] = ex;
    if (2 * t + 1 < NBUK + 1) shist[(2 * t + 1) * NBLK + b] = ex + d0;
    __syncthreads();
    #pragma unroll
    for (int i = 0; i < 16; i++) {
        int li = i * 256 + t;
        if (li < cnt) {
            int slot = atomicAdd(&cur[ed[i] >> 9], 1);
            lbuf[slot] = make_uint2(es[i], ed[i]);
        }
    }
    __syncthreads();
    for (int i = t; i < cnt; i += 256) region[base + i] = lbuf[i];
}

// per-bucket totals (one block per bucket, coalesced over chunks)
__global__ void bucket_tot_kernel(const int* __restrict__ shist, int* __restrict__ btot) {
    __shared__ int red[256];
    const int k = blockIdx.x, t = threadIdx.x;
    int s = 0;
    for (int b = t; b < NBLK; b += 256)
        s += shist[(k + 1) * NBLK + b] - shist[k * NBLK + b];
    red[t] = s;
    __syncthreads();
    for (int off = 128; off > 0; off >>= 1) {
        if (t < off) red[t] += red[t + off];
        __syncthreads();
    }
    if (t == 0) btot[k] = red[0];
}

// exclusive scan of 391 bucket totals -> bbase (single block, 512-pairwise)
__global__ void bucket_scan_kernel(const int* __restrict__ btot, int* __restrict__ bbase) {
    __shared__ int part[256];
    int t = threadIdx.x;
    int v0 = (2 * t < NBUK) ? btot[2 * t] : 0;
    int v1 = (2 * t + 1 < NBUK) ? btot[2 * t + 1] : 0;
    int s = v0 + v1;
    part[t] = s;
    __syncthreads();
    for (int off = 1; off < 256; off <<= 1) {
        int u = (t >= off) ? part[t - off] : 0;
        __syncthreads();
        part[t] += u;
        __syncthreads();
    }
    int ex = part[t] - s;
    if (2 * t < NBUK) bbase[2 * t] = ex;
    if (2 * t + 1 < NBUK) bbase[2 * t + 1] = ex + v0;
}

// pass B: one block per bucket -> LDS histogram + scan -> rowptr + col
__global__ __launch_bounds__(256) void csr_bucket_kernel(const uint2* __restrict__ region,
                                                         const int* __restrict__ shist,
                                                         const int* __restrict__ bbase,
                                                         int* __restrict__ rowptr,
                                                         int* __restrict__ col) {
    __shared__ int deg[512];
    __shared__ int part[256];
    __shared__ int cur[512];
    const int k = blockIdx.x, t = threadIdx.x;
    const int n0 = k * 512;
    const int nloc = min(512, NTOT - n0);
    const int base = bbase[k];
    deg[t] = 0; deg[t + 256] = 0;
    __syncthreads();
    for (int b = t; b < NBLK; b += 256) {
        int s0 = shist[k * NBLK + b], s1 = shist[(k + 1) * NBLK + b];
        for (int i = s0; i < s1; i++) {
            uint2 e = region[(size_t)b * CHUNK + i];
            atomicAdd(&deg[(int)e.y - n0], 1);
        }
    }
    __syncthreads();
    int d0 = deg[2 * t], d1 = deg[2 * t + 1];
    int s = d0 + d1;
    part[t] = s;
    __syncthreads();
    for (int off = 1; off < 256; off <<= 1) {
        int u = (t >= off) ? part[t - off] : 0;
        __syncthreads();
        part[t] += u;
        __syncthreads();
    }
    int ex = part[t] - s;
    cur[2 * t] = ex;
    cur[2 * t + 1] = ex + d0;
    if (2 * t < nloc) rowptr[n0 + 2 * t] = base + ex;
    if (2 * t + 1 < nloc) rowptr[n0 + 2 * t + 1] = base + ex + d0;
    if (t == 0 && n0 + nloc == NTOT) rowptr[NTOT] = base + part[255];
    __syncthreads();
    for (int b = t; b < NBLK; b += 256) {
        int s0 = shist[k * NBLK + b], s1 = shist[(k + 1) * NBLK + b];
        for (int i = s0; i < s1; i++) {
            uint2 e = region[(size_t)b * CHUNK + i];
            int pos = atomicAdd(&cur[(int)e.y - n0], 1);
            col[base + pos] = (int)e.x;
        }
    }
}

// ---------------- graph boundaries for both batches (batch sorted) ----------------
__global__ void brow2_kernel(const int* __restrict__ bs, const int* __restrict__ bt,
                             int* __restrict__ brow_s, int* __restrict__ brow_t) {
    int g = blockIdx.x * blockDim.x + threadIdx.x;
    const int* batch;
    int* brow;
    int gg;
    if (g <= BB) { batch = bs; brow = brow_s; gg = g; }
    else if (g <= 2 * BB + 1) { batch = bt; brow = brow_t; gg = g - (BB + 1); }
    else return;
    int lo = 0, hi = NN;
    while (lo < hi) {
        int mid = (lo + hi) >> 1;
        if (batch[mid] < gg) lo = mid + 1; else hi = mid;
    }
    brow[gg] = lo;
}

// ---------------- GAT aggregate, D=128 (combined): bf16 in, bf16 out ----------------
__global__ void gat_gather128_kernel(const int* __restrict__ rowptr, const int* __restrict__ col,
                                     const float* __restrict__ al_s, const float* __restrict__ al_d,
                                     const unsigned* __restrict__ hb,
                                     const float* __restrict__ bias_s,
                                     const float* __restrict__ bias_t,
                                     unsigned* __restrict__ outb) {
    int node = blockIdx.x * 4 + (threadIdx.x >> 6);
    int lane = threadIdx.x & 63;
    if (node >= NTOT) return;
    const float* bias = (node < NN) ? bias_s : bias_t;
    const int beg = rowptr[node], end = rowptr[node + 1];
    const float ald = al_d[node];
    const float e_self = leaky(al_s[node] + ald);

    float acc0 = 0.f, acc1 = 0.f, dsum = 0.f;
    for (int base = beg; base < end; base += 64) {
        int i = base + lane;
        float w = 0.f; int s = 0;
        if (i < end) {
            s = col[i];
            w = expf(leaky(al_s[s] + ald));   // no max shift: |e| small, f32-safe
        }
        dsum += w;
        int cnt = min(64, end - base);
        int j = 0;
        for (; j + 8 <= cnt; j += 8) {
            float wj[8]; int sj[8];
            #pragma unroll
            for (int u = 0; u < 8; u++) { wj[u] = __shfl(w, j + u); sj[u] = __shfl(s, j + u); }
            unsigned v[8];
            #pragma unroll
            for (int u = 0; u < 8; u++) v[u] = hb[(size_t)sj[u] * 64 + lane];
            #pragma unroll
            for (int u = 0; u < 8; u++) {
                acc0 += wj[u] * b2f_lo(v[u]);
                acc1 += wj[u] * b2f_hi(v[u]);
            }
        }
        for (; j < cnt; j++) {
            float wj = __shfl(w, j);
            int sj = __shfl(s, j);
            unsigned v = hb[(size_t)sj * 64 + lane];
            acc0 += wj * b2f_lo(v);
            acc1 += wj * b2f_hi(v);
        }
    }
    #pragma unroll
    for (int off = 32; off > 0; off >>= 1) dsum += __shfl_xor(dsum, off);

    float wself = expf(e_self);
    dsum += wself;
    float inv = 1.f / dsum;
    unsigned sv = hb[(size_t)node * 64 + lane];
    int c0 = 2 * lane, c1 = c0 + 1;
    float o0 = bias[c0] + (acc0 + wself * b2f_lo(sv)) * inv;
    float o1 = bias[c1] + (acc1 + wself * b2f_hi(sv)) * inv;
    outb[(size_t)node * 64 + lane] = packb(o0, o1);
}

// ---------------- GAT aggregate, D=64 (combined): two edges/pass; bf16 in, f32 out ----
__global__ void gat_gather64_kernel(const int* __restrict__ rowptr, const int* __restrict__ col,
                                    const float* __restrict__ al_s, const float* __restrict__ al_d,
                                    const unsigned* __restrict__ hb,
                                    const float* __restrict__ bias_s,
                                    const float* __restrict__ bias_t,
                                    float* __restrict__ out) {
    int node = blockIdx.x * 4 + (threadIdx.x >> 6);
    int lane = threadIdx.x & 63;
    if (node >= NTOT) return;
    const float* bias = (node < NN) ? bias_s : bias_t;
    const int sl = lane & 31, half = lane >> 5;
    const int beg = rowptr[node], end = rowptr[node + 1];
    const float ald = al_d[node];
    const float e_self = leaky(al_s[node] + ald);

    float acc0 = 0.f, acc1 = 0.f, dsum = 0.f;
    for (int base = beg; base < end; base += 64) {
        int i = base + lane;
        float w = 0.f; int s = 0;
        if (i < end) {
            s = col[i];
            w = expf(leaky(al_s[s] + ald));
        }
        dsum += w;
        int cnt = min(64, end - base);
        int j = 0;
        for (; j + 8 <= cnt; j += 8) {
            float wj[4]; int sj[4];
            #pragma unroll
            for (int u = 0; u < 4; u++) {
                int idx = j + 2 * u + half;
                wj[u] = __shfl(w, idx);
                sj[u] = __shfl(s, idx);
            }
            unsigned v[4];
            #pragma unroll
            for (int u = 0; u < 4; u++) v[u] = hb[(size_t)sj[u] * 32 + sl];
            #pragma unroll
            for (int u = 0; u < 4; u++) {
                acc0 += wj[u] * b2f_lo(v[u]);
                acc1 += wj[u] * b2f_hi(v[u]);
            }
        }
        for (; j < cnt; j += 2) {
            int idx = j + half;
            float wj = (idx < cnt) ? __shfl(w, idx) : 0.f;
            int sj = __shfl(s, idx < cnt ? idx : 0);
            unsigned v = hb[(size_t)sj * 32 + sl];
            acc0 += wj * b2f_lo(v);
            acc1 += wj * b2f_hi(v);
        }
    }
    acc0 += __shfl_xor(acc0, 32);
    acc1 += __shfl_xor(acc1, 32);
    #pragma unroll
    for (int off = 32; off > 0; off >>= 1) dsum += __shfl_xor(dsum, off);

    float wself = expf(e_self);
    dsum += wself;
    float inv = 1.f / dsum;
    if (half == 0) {
        unsigned sv = hb[(size_t)node * 32 + sl];
        float* op = out + (size_t)node * 64;
        int c0 = 2 * sl;
        float o0 = bias[c0] + (acc0 + wself * b2f_lo(sv)) * inv;
        float o1 = bias[c0 + 1] + (acc1 + wself * b2f_hi(sv)) * inv;
        *(float2*)(op + c0) = make_float2(o0, o1);
    }
}

// ---------------- segmented mean pool, both branches: one block per (branch, graph) ---
__global__ void pool_seg_kernel(const float* __restrict__ x,
                                const int* __restrict__ brow_s, const int* __restrict__ brow_t,
                                float* __restrict__ pooled_s, float* __restrict__ pooled_t) {
    __shared__ float red[4][64];
    int g = blockIdx.x;
    int tb = g >= BB;
    int gb = g - tb * BB;
    const int* brow = tb ? brow_t : brow_s;
    float* pooled = tb ? pooled_t : pooled_s;
    int off = tb ? NN : 0;
    int lane = threadIdx.x & 63, w = threadIdx.x >> 6;
    int beg = brow[gb], end = brow[gb + 1];
    float acc = 0.f;
    for (int n = beg + w; n < end; n += 4)
        acc += x[(size_t)(off + n) * 64 + lane];
    red[w][lane] = acc;
    __syncthreads();
    if (w == 0) {
        float s = red[0][lane] + red[1][lane] + red[2][lane] + red[3][lane];
        float cnt = (float)(end - beg);
        pooled[(size_t)gb * 64 + lane] = s / fmaxf(cnt, 1.f);
    }
}

// ---------------- final: sigmoid((xs+xt)@lin_w + lin_b) ----------------
__global__ void final_kernel(const float* __restrict__ ps, const float* __restrict__ pt,
                             const float* __restrict__ lw, const float* __restrict__ lb,
                             float* __restrict__ out) {
    int g = blockIdx.x;
    int c = threadIdx.x;
    if (c >= 27) return;
    float acc = lb[c];
    #pragma unroll 8
    for (int k = 0; k < 64; k++) {
        float xv = ps[g * 64 + k] + pt[g * 64 + k];
        acc += xv * lw[k * 27 + c];
    }
    out[g * 27 + c] = 1.f / (1.f + expf(-acc));
}

extern "C" void kernel_launch(void* const* d_in, const int* in_sizes, int n_in,
                              void* d_out, int out_size, void* d_ws, size_t ws_size,
                              hipStream_t stream) {
    const float* x_s = (const float*)d_in[0];
    const float* x_t = (const float*)d_in[1];
    const int* ei_s = (const int*)d_in[2];
    const int* ei_t = (const int*)d_in[3];
    const int* xs_batch = (const int*)d_in[4];
    const int* xt_batch = (const int*)d_in[5];
    const float* W_s1 = (const float*)d_in[6];
    const float* a_src_s1 = (const float*)d_in[7];
    const float* a_dst_s1 = (const float*)d_in[8];
    const float* b_s1 = (const float*)d_in[9];
    const float* W_s2 = (const float*)d_in[10];
    const float* a_src_s2 = (const float*)d_in[11];
    const float* a_dst_s2 = (const float*)d_in[12];
    const float* b_s2 = (const float*)d_in[13];
    const float* W_t1 = (const float*)d_in[14];
    const float* a_src_t1 = (const float*)d_in[15];
    const float* a_dst_t1 = (const float*)d_in[16];
    const float* b_t1 = (const float*)d_in[17];
    const float* W_t2 = (const float*)d_in[18];
    const float* a_src_t2 = (const float*)d_in[19];
    const float* a_dst_t2 = (const float*)d_in[20];
    const float* b_t2 = (const float*)d_in[21];
    const float* lin_w = (const float*)d_in[22];
    const float* lin_b = (const float*)d_in[23];
    float* out = (float*)d_out;

    // workspace carve-up (dword units). Aliases: region <-> hb (disjoint in time),
    // out2 <-> out1b (out1b dead after gemm2 reads it).
    unsigned* hb = (unsigned*)d_ws;                        // NTOT*64 dw (51.2 MB)
    uint2* region = (uint2*)d_ws;                          // NBLK*CHUNK uint2 (25.6 MB) alias
    unsigned* out1b = hb + (size_t)NTOT * 64;              // NTOT*64 dw (51.2 MB)
    float* out2 = (float*)out1b;                           // alias (used after gemm2)
    int* col = (int*)(out1b + (size_t)NTOT * 64);          // ETOT
    float* al_s = (float*)(col + ETOT);                    // NTOT
    float* al_d = al_s + NTOT;                             // NTOT
    float* pooled_s = al_d + NTOT;                         // BB*64
    float* pooled_t = pooled_s + (size_t)BB * 64;          // BB*64
    unsigned short* WT1 = (unsigned short*)(pooled_t + (size_t)BB * 64);  // 2*128*256
    unsigned short* WT2 = WT1 + 2 * 256 * 128;             // 2*64*128
    int* rowptr = (int*)(WT2 + 2 * 128 * 64);              // NTOT+1
    int* shist = rowptr + NTOT + 1;                        // (NBUK+1)*NBLK
    int* btot = shist + (NBUK + 1) * NBLK;                 // NBUK
    int* bbase = btot + NBUK;                              // NBUK
    int* brow_s = bbase + NBUK;                            // BB+1
    int* brow_t = brow_s + BB + 1;                         // BB+1

    const int* src_s = ei_s;
    const int* dst_s = ei_s + EE;
    const int* src_t = ei_t;
    const int* dst_t = ei_t + EE;

    // ----- CSR build (combined graph) -----
    bin_sort_kernel<<<NBLK, 256, 0, stream>>>(src_s, dst_s, src_t, dst_t, region, shist);
    bucket_tot_kernel<<<NBUK, 256, 0, stream>>>(shist, btot);
    bucket_scan_kernel<<<1, 256, 0, stream>>>(btot, bbase);
    csr_bucket_kernel<<<NBUK, 256, 0, stream>>>(region, shist, bbase, rowptr, col);

    // ----- layer 1 (both branches) -----
    wt2_kernel<<<(2 * 256 * 128 + 255) / 256, 256, 0, stream>>>(W_s1, W_t1, WT1, 256, 128);
    gemm_fused_kernel<256, 128, false><<<2 * GB, 256, 0, stream>>>(
        x_s, x_t, WT1, a_src_s1, a_dst_s1, a_src_t1, a_dst_t1, hb, al_s, al_d, GB);
    gat_gather128_kernel<<<(NTOT + 3) / 4, 256, 0, stream>>>(
        rowptr, col, al_s, al_d, hb, b_s1, b_t1, out1b);

    // ----- layer 2 (both branches) -----
    wt2_kernel<<<(2 * 128 * 64 + 255) / 256, 256, 0, stream>>>(W_s2, W_t2, WT2, 128, 64);
    gemm_fused_kernel<128, 64, true><<<2 * GB, 256, 0, stream>>>(
        out1b, (const unsigned short*)out1b + (size_t)NN * 128, WT2,
        a_src_s2, a_dst_s2, a_src_t2, a_dst_t2, hb, al_s, al_d, GB);
    gat_gather64_kernel<<<(NTOT + 3) / 4, 256, 0, stream>>>(
        rowptr, col, al_s, al_d, hb, b_s2, b_t2, out2);

    // ----- pool + head -----
    brow2_kernel<<<(2 * (BB + 1) + 255) / 256, 256, 0, stream>>>(xs_batch, xt_batch, brow_s, brow_t);
    pool_seg_kernel<<<2 * BB, 256, 0, stream>>>(out2, brow_s, brow_t, pooled_s, pooled_t);
    final_kernel<<<BB, 32, 0, stream>>>(pooled_s, pooled_t, lin_w, lin_b, out);
}